// Round 1
// 516.994 us; speedup vs baseline: 1.0654x; 1.0654x over previous
//
#include <hip/hip_runtime.h>
#include <cstdint>

// HungarianMatcher cost via MFMA, round 4.
// R1: LDS-atomic histogram = DS-pipe-bound (815us).
// R2: on-the-fly per-wave B build = 140 VALU/step (240us).
// R3: Bpre precompute (226us) - but 7 B-loads/wave/step x4 waves duplicated,
//     and cb/nb double-buffer (56 VGPRs) capped occupancy at 3 waves/SIMD
//     (88 VGPR + 56 acc = 144 unified regs). All pipes <35% => latency-bound.
// R4 fix: B fragments are IDENTICAL across the block's 4 waves (same K-range,
//     different q-strips). Build them once per block into LDS (each wave
//     builds <=2 tiles from L2-hot labels, ~40 VALU/wave/step), double-
//     buffered, one barrier/step. Kills cb/nb regs -> __launch_bounds__(256,4)
//     = 4 waves/SIMD; VMEM 9 -> 4 instrs/wave/step; deletes build_B kernel
//     and the 90 MB Bpre HBM round-trip. KC 110 -> 146 (1022 blocks ~ 4/CU).

#define FOCAL_ALPHA 0.25f
constexpr int NMAX   = 128;
constexpr int NTILES = 7;      // 7 x 16 = 112 cols >= N=100
constexpr int BLOCK  = 256;    // 4 waves, each owns one 16-row q-strip
constexpr int KC     = 146;    // 146*7 = 1022 blocks ~ 4 blocks/CU, one round

typedef __attribute__((ext_vector_type(8))) short short8;
typedef __attribute__((ext_vector_type(4))) float f32x4;

union BU { uint4 q; short8 v; uint32_t u[4]; };

// 17 VALU ops (3 quarter-rate trans). Safe for |x| < 80 (inputs ~N(0,1)).
__device__ __forceinline__ void point_math(float x, float& d, float& f0o, float& po) {
    float e  = __expf(-x);                      // e^{-x}
    float a  = 1.0f + e;
    float p  = __builtin_amdgcn_rcpf(a);        // sigmoid(x)
    float l  = __logf(a);                       // -log sigmoid(x)
    float lm = -x - l;                          // log(1 - sigmoid(x))
    float om = e * p;                           // 1 - p
    float f1 = FOCAL_ALPHA * (om * om) * l;     // -a(1-p)^2 log p
    float f0 = -(1.0f - FOCAL_ALPHA) * (p * p) * lm;
    d   = f1 - f0;
    f0o = f0;
    po  = p;
}

// pack two fp32 into bf16x2 by truncation, single v_perm
__device__ __forceinline__ uint32_t pack_bf16_trunc(float lo, float hi) {
    return __builtin_amdgcn_perm(__float_as_uint(hi), __float_as_uint(lo), 0x07060302u);
}

__global__ __launch_bounds__(BLOCK, 4) void
matcher_main(const float* __restrict__ pred, const int* __restrict__ labels,
             float* __restrict__ S1, float* __restrict__ S2,
             float* __restrict__ sumf0, float* __restrict__ sump,
             int Q, int P, int N) {
    // double-buffered shared B fragments: [buf][tile][lane] = uint4 (8 bf16)
    __shared__ uint4 Bl[2][NTILES][64];

    const int tid  = threadIdx.x;
    const int wave = tid >> 6;
    const int lane = tid & 63;
    const int m    = lane & 15;
    const int quad = lane >> 4;

    const int strip = blockIdx.y * 4 + wave;
    const int q0    = strip * 16;
    const bool alive = (q0 < Q);           // wave-uniform; dead waves still
                                           // build B + hit barriers

    const int total_steps = P >> 5;
    const int per         = (total_steps + KC - 1) / KC;
    const int s0          = blockIdx.x * per;
    const int s1          = min(s0 + per, total_steps);
    if (s0 >= s1) return;                  // block-uniform: no barrier reached

    // tile assignment for the shared B build: wave w builds tiles w, w+4
    const int  t0   = wave;
    const int  t1   = wave + 4;
    const bool has2 = (t1 < NTILES);
    const int  tgt0 = t0 * 16 + m;
    const int  tgt1 = t1 * 16 + m;

    const int*   lr = labels + (size_t)s0 * 32 + quad * 8;
    const float* pr = pred + (size_t)(q0 + m) * P + quad * 8 + (size_t)s0 * 32;

    f32x4 c1[NTILES], c2[NTILES];
    #pragma unroll
    for (int t = 0; t < NTILES; ++t) {
        c1[t] = (f32x4){0.f, 0.f, 0.f, 0.f};
        c2[t] = (f32x4){0.f, 0.f, 0.f, 0.f};
    }
    float sf0 = 0.0f, sp = 0.0f;

    // Build B fragments for the 32 labels at lp into LDS buffer `buf`.
    // Fragment layout identical to R3's build_B kernel (harness-verified):
    // lane (m,quad), reg i holds bf16 one-hot for points quad*8 + {2i,2i+1}.
    auto build = [&](const int* lp, int buf) {
        int4 l0 = *(const int4*)lp;
        int4 l1 = *(const int4*)(lp + 4);
        const int ls[8] = {l0.x, l0.y, l0.z, l0.w, l1.x, l1.y, l1.z, l1.w};
        BU B0;
        #pragma unroll
        for (int i = 0; i < 4; ++i) {
            uint32_t lo = (ls[2*i]   == tgt0) ? 0x00003F80u : 0u;
            uint32_t hi = (ls[2*i+1] == tgt0) ? 0x3F800000u : 0u;
            B0.u[i] = lo | hi;
        }
        Bl[buf][t0][lane] = B0.q;
        if (has2) {
            BU B1;
            #pragma unroll
            for (int i = 0; i < 4; ++i) {
                uint32_t lo = (ls[2*i]   == tgt1) ? 0x00003F80u : 0u;
                uint32_t hi = (ls[2*i+1] == tgt1) ? 0x3F800000u : 0u;
                B1.u[i] = lo | hi;
            }
            Bl[buf][t1][lane] = B1.q;
        }
    };

    float4 cx0, cx1;
    if (alive) {
        cx0 = *(const float4*)pr;
        cx1 = *(const float4*)(pr + 4);
    }
    build(lr, 0);
    __syncthreads();

    for (int s = s0; s < s1; ++s) {
        const int  ph   = (s - s0) & 1;    // read Bl[ph], write Bl[ph^1]
        const bool more = (s + 1 < s1);    // block-uniform

        lr += 32;
        if (more) build(lr, ph ^ 1);

        if (alive) {
            float4 nx0, nx1;
            if (more) {                     // prefetch next pred step
                nx0 = *(const float4*)(pr + 32);
                nx1 = *(const float4*)(pr + 36);
            }

            const float xs[8] = {cx0.x, cx0.y, cx0.z, cx0.w,
                                 cx1.x, cx1.y, cx1.z, cx1.w};
            BU A1, A2;
            #pragma unroll
            for (int i = 0; i < 4; ++i) {
                float d0, f0a, p0, d1, f0b, p1;
                point_math(xs[2*i],     d0, f0a, p0);
                point_math(xs[2*i + 1], d1, f0b, p1);
                sf0 += f0a + f0b;
                sp  += p0 + p1;
                A1.u[i] = pack_bf16_trunc(d0, d1);
                A2.u[i] = pack_bf16_trunc(p0, p1);
            }

            #pragma unroll
            for (int t = 0; t < NTILES; ++t) {
                BU B;
                B.q = Bl[ph][t][lane];
                c1[t] = __builtin_amdgcn_mfma_f32_16x16x32_bf16(A1.v, B.v, c1[t], 0, 0, 0);
                c2[t] = __builtin_amdgcn_mfma_f32_16x16x32_bf16(A2.v, B.v, c2[t], 0, 0, 0);
            }
            pr += 32;
            cx0 = nx0; cx1 = nx1;
        }
        __syncthreads();   // Bl[ph] reads drained (lgkmcnt) before next step
                           // overwrites it; Bl[ph^1] writes visible
    }

    if (alive) {
        float a = sf0, b = sp;
        a += __shfl_xor(a, 16, 64);
        a += __shfl_xor(a, 32, 64);
        b += __shfl_xor(b, 16, 64);
        b += __shfl_xor(b, 32, 64);
        if (lane < 16) {
            unsafeAtomicAdd(&sumf0[q0 + lane], a);
            unsafeAtomicAdd(&sump[q0 + lane], b);
        }

        // C/D layout: col = lane&15 (+16t), row = quad*4 + reg
        #pragma unroll
        for (int t = 0; t < NTILES; ++t) {
            const int col = t * 16 + m;
            if (col < N) {
                #pragma unroll
                for (int r = 0; r < 4; ++r) {
                    const int row = q0 + quad * 4 + r;
                    unsafeAtomicAdd(&S1[(size_t)row * N + col], c1[t][r]);
                    unsafeAtomicAdd(&S2[(size_t)row * N + col], c2[t][r]);
                }
            }
        }
    }
}

__global__ __launch_bounds__(256) void
matcher_counts(const int* __restrict__ labels, int* __restrict__ counts, int P, int N) {
    __shared__ int c[NMAX];
    for (int i = threadIdx.x; i < NMAX; i += 256) c[i] = 0;
    __syncthreads();
    const int stride = gridDim.x * 256;
    for (int i = blockIdx.x * 256 + threadIdx.x; i < P; i += stride)
        atomicAdd(&c[labels[i]], 1);
    __syncthreads();
    for (int j = threadIdx.x; j < N; j += 256)
        if (c[j] != 0) atomicAdd(&counts[j], c[j]);
}

__global__ __launch_bounds__(256) void
matcher_final(const float* __restrict__ S1, const float* __restrict__ S2,
              const float* __restrict__ sumf0, const float* __restrict__ sump,
              const int* __restrict__ counts, float* __restrict__ out,
              int Q, int P, int N) {
    int idx = blockIdx.x * 256 + threadIdx.x;
    if (idx >= Q * N) return;
    int q = idx / N;
    int j = idx - q * N;
    float invP = 1.0f / (float)P;
    float cost_mask = (S1[idx] + sumf0[q]) * invP;
    float cost_dice = 1.0f - (2.0f * S2[idx] + 1.0f) / (sump[q] + (float)counts[j] + 1.0f);
    out[idx] = cost_mask + cost_dice;
}

extern "C" void kernel_launch(void* const* d_in, const int* in_sizes, int n_in,
                              void* d_out, int out_size, void* d_ws, size_t ws_size,
                              hipStream_t stream) {
    const float* pred   = (const float*)d_in[0];
    const int*   labels = (const int*)d_in[1];
    const int P = in_sizes[1];
    const int Q = in_sizes[0] / P;
    const int N = out_size / Q;

    float* S1     = (float*)d_ws;
    float* S2     = S1 + (size_t)Q * N;
    float* sumf0  = S2 + (size_t)Q * N;
    float* sump   = sumf0 + Q;
    int*   counts = (int*)(sump + Q);
    size_t base_bytes = ((size_t)2 * Q * N + 2 * Q + N) * sizeof(float);

    hipMemsetAsync(d_ws, 0, base_bytes, stream);
    matcher_counts<<<64, 256, 0, stream>>>(labels, counts, P, N);

    const int strips = (Q + 15) / 16;
    dim3 grid(KC, (strips + 3) / 4);
    matcher_main<<<grid, BLOCK, 0, stream>>>(pred, labels, S1, S2, sumf0, sump, Q, P, N);

    int qn = Q * N;
    matcher_final<<<(qn + 255) / 256, 256, 0, stream>>>(S1, S2, sumf0, sump, counts,
                                                        (float*)d_out, Q, P, N);
}